// Round 4
// baseline (525.950 us; speedup 1.0000x reference)
//
#include <hip/hip_runtime.h>
#include <hip/hip_bf16.h>
#include <math.h>

// Problem constants (S, B, D_IN, D_SRC, D_ALIGN = 2048, 64, 512, 512, 512)
#define S_LEN 2048
#define BATCH 64
#define DDIM 512

typedef __attribute__((ext_vector_type(8))) short bf16x8;
typedef __attribute__((ext_vector_type(4))) float f32x4;
typedef __attribute__((ext_vector_type(4))) unsigned int u32x4;

__device__ __forceinline__ unsigned short f2bf(float f) {
  unsigned int u = __float_as_uint(f);
  u += 0x7fffu + ((u >> 16) & 1u);
  return (unsigned short)(u >> 16);
}

__device__ __forceinline__ float tanh_fast(float x) {
  // tanh(x) = 1 - 2/(exp2(2*log2e*x)+1)
  float e = __builtin_amdgcn_exp2f(x * 2.88539008177793f);
  return 1.0f - 2.0f * __builtin_amdgcn_rcpf(e + 1.0f);
}

// pack two f32 into bf16x2 (lo=a, hi=b), round-half-up (matches prior kernel)
__device__ __forceinline__ unsigned pkbf(float a, float b) {
  unsigned ua = __float_as_uint(a) + 0x8000u;
  unsigned ub = __float_as_uint(b) + 0x8000u;
  return __builtin_amdgcn_perm(ub, ua, 0x07060302u);
}

// ---------------------------------------------------------------------------
// prep: W1bT[kc][n][e] = bf16(W1[n][512 + kc*8 + e])  (k-chunk-major so scores
// can load B fragments straight from L2, coalesced 256B per 16-lane group);
// uprime[b][a] = b1[a] + W1[a,:512].input[b]
// ---------------------------------------------------------------------------
__global__ __launch_bounds__(256) void prep_kernel(
    const float* __restrict__ W1, const float* __restrict__ b1,
    const float* __restrict__ input, unsigned short* __restrict__ W1bT,
    float* __restrict__ uprime) {
  __shared__ float w1row[1024];
  const int a = blockIdx.x;
  const int t = threadIdx.x;
  float4 v = *(const float4*)(W1 + a * 1024 + t * 4);
  *(float4*)(w1row + t * 4) = v;
  if (t >= 128) {
    ushort4 u;
    u.x = f2bf(v.x); u.y = f2bf(v.y); u.z = f2bf(v.z); u.w = f2bf(v.w);
    const int d = t * 4 - 512;       // 0..508 step 4
    const int kc = d >> 3;           // k-chunk 0..63
    const int e = d & 7;             // 0 or 4
    *(ushort4*)(W1bT + ((size_t)kc * 512 + a) * 8 + e) = u;
  }
  __syncthreads();
  if (t < BATCH) {
    const float4* inp = (const float4*)(input + t * 512);
    const float4* wr = (const float4*)w1row;
    float acc = b1[a];
#pragma unroll 4
    for (int d = 0; d < 128; ++d) {
      float4 x = inp[d], w = wr[d];
      acc += x.x * w.x + x.y * w.y + x.z * w.z + x.w * w.w;
    }
    uprime[t * 512 + a] = acc;  // [b][a]
  }
}

// ---------------------------------------------------------------------------
// scores v8: BM=64 (one s per block, grid 2048), 256 thr / 4 waves.
// Wave w owns cols [p*256 + w*64, +64) in TWO N-passes over a full-K LDS
// A-tile -> acc[4][4] (64 regs), leaving VGPR headroom for MANUAL
// double-buffered fragments: step n+1's B-globals (L2) and A-ds_reads are
// issued BEFORE step n's MFMAs, so the ~220cyc L2 latency hides under the
// MFMA burst (v7's VGPR_Count=92 proved the compiler serialized instead).
// Block-parity K-stagger (kk = n ^ (s&1)*8) anti-aligns the two co-resident
// blocks' stall phases and spreads their W1bT L2 streams. s_setprio(1)
// around each MFMA burst (T5) exploits the resulting phase diversity.
// One barrier total. LDS 64.3 KB -> 2 blocks/CU.
// ---------------------------------------------------------------------------
__global__ __launch_bounds__(256, 2) void scores_kernel(
    const float* __restrict__ src, const unsigned short* __restrict__ W1bT,
    const float* __restrict__ uprime, const float* __restrict__ W2,
    float* __restrict__ scores_t) {
  __shared__ unsigned short A_sm[64 * 512];  // 64 KB, full-K A tile
  __shared__ float s_lds[BATCH];

  const int t = threadIdx.x;
  const int s = blockIdx.x;    // one s per block
  const int w = t >> 6;        // wave 0..3 (uniform)
  const int lane = t & 63;
  const int quad = lane >> 4;
  const int l15 = lane & 15;
  const int stag8 = (s & 1) << 3;  // K-stagger: odd blocks start at kk=8

  if (t < BATCH) s_lds[t] = 0.f;

  // ---- stage full A tile: 64 rows x 512 f32 -> bf16, swizzled chunks ----
  {
    const float4* gsrc = (const float4*)(src + (size_t)s * (BATCH * DDIM));
    const int cc = t & 63;
#pragma unroll 4
    for (int n = 0; n < 16; ++n) {
      const int row = n * 4 + (t >> 6);
      const float4 v0 = gsrc[row * 128 + cc * 2];
      const float4 v1 = gsrc[row * 128 + cc * 2 + 1];
      u32x4 o;
      o.x = pkbf(v0.x, v0.y);
      o.y = pkbf(v0.z, v0.w);
      o.z = pkbf(v1.x, v1.y);
      o.w = pkbf(v1.z, v1.w);
      const int p = cc ^ (row & 7);
      *(u32x4*)(A_sm + row * 512 + p * 8) = o;
    }
  }
  __syncthreads();  // the ONLY barrier

// fragment load macros (static dst regs -> stays in VGPRs, rule #20)
#define LOADB(dst, nn, pcol)                                                   \
  {                                                                            \
    const int kcb = ((nn) ^ stag8) * 4 + quad;                                 \
    _Pragma("unroll") for (int j_ = 0; j_ < 4; ++j_) dst[j_] =                 \
        *(const bf16x8*)(W1bT + ((size_t)kcb * 512 + (pcol) + j_ * 16) * 8);   \
  }
#define LOADA(dst, nn)                                                         \
  {                                                                            \
    const int cb = ((nn) ^ stag8) * 4 + quad;                                  \
    _Pragma("unroll") for (int i_ = 0; i_ < 4; ++i_) {                         \
      const int r_ = i_ * 16 + l15;                                            \
      dst[i_] = *(const bf16x8*)(A_sm + r_ * 512 + ((cb ^ (r_ & 7)) << 3));    \
    }                                                                          \
  }
#define MFMA16(af, bb)                                                         \
  {                                                                            \
    __builtin_amdgcn_s_setprio(1);                                             \
    _Pragma("unroll") for (int i_ = 0; i_ < 4; ++i_)                           \
        _Pragma("unroll") for (int j_ = 0; j_ < 4; ++j_) acc[i_][j_] =         \
            __builtin_amdgcn_mfma_f32_16x16x32_bf16(af[i_], bb[j_],            \
                                                    acc[i_][j_], 0, 0, 0);     \
    __builtin_amdgcn_s_setprio(0);                                             \
  }

#pragma unroll
  for (int p = 0; p < 2; ++p) {
    const int pcol = p * 256 + w * 64 + l15;  // this wave's col base (+j*16)

    f32x4 acc[4][4];
#pragma unroll
    for (int i = 0; i < 4; ++i)
#pragma unroll
      for (int j = 0; j < 4; ++j) acc[i][j] = (f32x4){0.f, 0.f, 0.f, 0.f};

    bf16x8 bbA[4], bbB[4], afA[4], afB[4];
    LOADB(bbA, 0, pcol);
    LOADA(afA, 0);
#pragma unroll
    for (int n = 0; n < 16; n += 2) {
      // prefetch step n+1 while MFMAing step n
      LOADB(bbB, n + 1, pcol);
      LOADA(afB, n + 1);
      MFMA16(afA, bbA);
      if (n + 2 < 16) {
        LOADB(bbA, n + 2, pcol);
        LOADA(afA, n + 2);
      }
      MFMA16(afB, bbB);
    }

    // ---- epilogue pass p: tanh + W2 partial dot over these 64 cols ----
    float w2r[4];
#pragma unroll
    for (int j = 0; j < 4; ++j) w2r[j] = W2[pcol + j * 16];

#pragma unroll
    for (int i = 0; i < 4; ++i) {
#pragma unroll
      for (int r = 0; r < 4; ++r) {
        const int b = i * 16 + quad * 4 + r;  // batch row 0..63
        const float* up = uprime + b * 512 + pcol;
        float sp = 0.f;
#pragma unroll
        for (int j = 0; j < 4; ++j)
          sp += w2r[j] * tanh_fast(acc[i][j][r] + up[j * 16]);
        sp += __shfl_xor(sp, 1);
        sp += __shfl_xor(sp, 2);
        sp += __shfl_xor(sp, 4);
        sp += __shfl_xor(sp, 8);
        if (l15 == 0) atomicAdd(&s_lds[b], sp);
      }
    }
  }
#undef LOADB
#undef LOADA
#undef MFMA16

  __syncthreads();
  if (t < BATCH) scores_t[t * S_LEN + s] = s_lds[t];  // transposed [b][s]
}

// ---------------------------------------------------------------------------
// softmax over s per b; reads contiguous scores_t[b][s]. Writes attn[s][b]
// (output) and optionally attn_t[b][s] (ws, contiguous for ctx).
// ---------------------------------------------------------------------------
__global__ __launch_bounds__(256) void softmax_kernel(
    const float* __restrict__ scores_t, const unsigned char* __restrict__ mask,
    float* __restrict__ attn_g, float* __restrict__ attn_t, int write_t) {
  __shared__ float red[256];
  const int b = blockIdx.x, t = threadIdx.x;
  float m = -__builtin_inff();
  float sc[8];
#pragma unroll
  for (int c = 0; c < 8; ++c) {
    const int s = t + c * 256;
    sc[c] = mask[s * BATCH + b] ? -__builtin_inff() : scores_t[b * S_LEN + s];
    m = fmaxf(m, sc[c]);
  }
  red[t] = m;
  __syncthreads();
  for (int off = 128; off; off >>= 1) {
    if (t < off) red[t] = fmaxf(red[t], red[t + off]);
    __syncthreads();
  }
  m = red[0];
  __syncthreads();
  float sum = 0.f;
#pragma unroll
  for (int c = 0; c < 8; ++c) sum += __expf(sc[c] - m);
  red[t] = sum;
  __syncthreads();
  for (int off = 128; off; off >>= 1) {
    if (t < off) red[t] += red[t + off];
    __syncthreads();
  }
  const float inv = 1.f / red[0];
#pragma unroll
  for (int c = 0; c < 8; ++c) {
    const int s = t + c * 256;
    const float p = __expf(sc[c] - m) * inv;
    attn_g[s * BATCH + b] = p;
    if (write_t) attn_t[b * S_LEN + s] = p;
  }
}

// ---------------------------------------------------------------------------
// ctx two-stage (no atomics). Stage 1: grid (32 s-chunks, 64 b), each block
// computes two 32-s half-partials (float4 stores, coalesced).
// ---------------------------------------------------------------------------
__global__ __launch_bounds__(256) void ctx_partial_kernel(
    const float* __restrict__ src, const float* __restrict__ attn_t,
    float* __restrict__ partial) {
  __shared__ float a_lds[64];
  const int c = blockIdx.x;  // 0..31
  const int b = blockIdx.y;  // 0..63
  const int t = threadIdx.x;
  if (t < 64) a_lds[t] = attn_t[b * S_LEN + c * 64 + t];
  __syncthreads();
  const int f4i = t & 127;
  const int sh = t >> 7;
  const float4* base =
      (const float4*)src + ((size_t)(c * 64 + sh * 32) * BATCH + b) * 128 + f4i;
  float4 acc = {0.f, 0.f, 0.f, 0.f};
#pragma unroll 8
  for (int i = 0; i < 32; ++i) {
    const float a = a_lds[sh * 32 + i];
    float4 v = base[(size_t)i * BATCH * 128];
    acc.x += a * v.x; acc.y += a * v.y; acc.z += a * v.z; acc.w += a * v.w;
  }
  ((float4*)partial)[((size_t)(c * 2 + sh) * BATCH + b) * 128 + f4i] = acc;
}

// Stage 2: ctx[b][d] = sum over 64 half-partials. grid 64, 256 thr (float2/thr).
__global__ __launch_bounds__(256) void ctx_reduce_kernel(
    const float* __restrict__ partial, float* __restrict__ ctx) {
  const int b = blockIdx.x, t = threadIdx.x;
  const float2* p = (const float2*)partial + (size_t)b * 256 + t;
  float2 acc = {0.f, 0.f};
#pragma unroll 8
  for (int c2 = 0; c2 < 64; ++c2) {
    float2 v = p[(size_t)c2 * BATCH * 256];
    acc.x += v.x; acc.y += v.y;
  }
  ((float2*)ctx)[b * 256 + t] = acc;
}

// Fallback ctx (small ws): atomicAdd into zeroed ctx, reads attn [s][b].
__global__ __launch_bounds__(256) void ctx_atomic_kernel(
    const float* __restrict__ src, const float* __restrict__ attn_g,
    float* __restrict__ ctx) {
  __shared__ float a_lds[128];
  const int s0 = blockIdx.x * 128, b = blockIdx.y, t = threadIdx.x;
  if (t < 128) a_lds[t] = attn_g[(s0 + t) * BATCH + b];
  __syncthreads();
  const int f4i = t & 127;
  const int sh = t >> 7;
  const float4* base =
      (const float4*)src + ((size_t)(s0 + sh * 64) * BATCH + b) * 128 + f4i;
  float4 acc = {0.f, 0.f, 0.f, 0.f};
#pragma unroll 8
  for (int i = 0; i < 64; ++i) {
    const float a = a_lds[sh * 64 + i];
    float4 v = base[(size_t)i * BATCH * 128];
    acc.x += a * v.x; acc.y += a * v.y; acc.z += a * v.z; acc.w += a * v.w;
  }
  float* cp = ctx + b * DDIM + f4i * 4;
  atomicAdd(cp + 0, acc.x);
  atomicAdd(cp + 1, acc.y);
  atomicAdd(cp + 2, acc.z);
  atomicAdd(cp + 3, acc.w);
}

// ---------------------------------------------------------------------------
extern "C" void kernel_launch(void* const* d_in, const int* in_sizes, int n_in,
                              void* d_out, int out_size, void* d_ws, size_t ws_size,
                              hipStream_t stream) {
  const float* input = (const float*)d_in[0];
  const float* src = (const float*)d_in[1];
  const unsigned char* mask = (const unsigned char*)d_in[2];
  const float* W1 = (const float*)d_in[3];
  const float* b1 = (const float*)d_in[4];
  const float* W2 = (const float*)d_in[5];
  // d_in[6] = b2: omitted (constant shift cancels in softmax)

  float* ctx = (float*)d_out;                  // [64,512]
  float* attn = (float*)d_out + BATCH * DDIM;  // [2048,64]

  // ws layout
  unsigned short* W1bT = (unsigned short*)d_ws;                       // 512 KB
  float* uprime = (float*)((char*)d_ws + 512 * 1024);                 // 128 KB
  float* scores_t = (float*)((char*)d_ws + 640 * 1024);               // 512 KB
  float* attn_t = (float*)((char*)d_ws + 1152 * 1024);                // 512 KB
  float* partial = (float*)((char*)d_ws + 1664 * 1024);               // 8 MB
  const size_t NEED_ATTN_T = 1664 * 1024;
  const size_t NEED_PARTIAL = 1664 * 1024 + (size_t)64 * BATCH * DDIM * 4;
  const int have_attn_t = ws_size >= NEED_ATTN_T;
  const int have_partial = ws_size >= NEED_PARTIAL;

  prep_kernel<<<512, 256, 0, stream>>>(W1, b1, input, W1bT, uprime);
  scores_kernel<<<S_LEN, 256, 0, stream>>>(src, W1bT, uprime, W2, scores_t);
  softmax_kernel<<<BATCH, 256, 0, stream>>>(scores_t, mask, attn, attn_t,
                                            have_attn_t && have_partial);
  if (have_partial) {
    ctx_partial_kernel<<<dim3(32, BATCH), 256, 0, stream>>>(src, attn_t, partial);
    ctx_reduce_kernel<<<BATCH, 256, 0, stream>>>(partial, ctx);
  } else {
    hipMemsetAsync(ctx, 0, BATCH * DDIM * sizeof(float), stream);
    ctx_atomic_kernel<<<dim3(16, BATCH), 256, 0, stream>>>(src, attn, ctx);
  }
}

// Round 5
// 477.050 us; speedup vs baseline: 1.1025x; 1.1025x over previous
//
#include <hip/hip_runtime.h>
#include <hip/hip_bf16.h>
#include <math.h>

// Problem constants (S, B, D_IN, D_SRC, D_ALIGN = 2048, 64, 512, 512, 512)
#define S_LEN 2048
#define BATCH 64
#define DDIM 512

typedef __attribute__((ext_vector_type(8))) short bf16x8;
typedef __attribute__((ext_vector_type(4))) float f32x4;
typedef __attribute__((ext_vector_type(4))) unsigned int u32x4;

__device__ __forceinline__ unsigned short f2bf(float f) {
  unsigned int u = __float_as_uint(f);
  u += 0x7fffu + ((u >> 16) & 1u);
  return (unsigned short)(u >> 16);
}

__device__ __forceinline__ float tanh_fast(float x) {
  // tanh(x) = 1 - 2/(exp2(2*log2e*x)+1)
  float e = __builtin_amdgcn_exp2f(x * 2.88539008177793f);
  return 1.0f - 2.0f * __builtin_amdgcn_rcpf(e + 1.0f);
}

// pack two f32 into bf16x2 (lo=a, hi=b), round-half-up (matches prior kernel)
__device__ __forceinline__ unsigned pkbf(float a, float b) {
  unsigned ua = __float_as_uint(a) + 0x8000u;
  unsigned ub = __float_as_uint(b) + 0x8000u;
  return __builtin_amdgcn_perm(ub, ua, 0x07060302u);
}

// ---------------------------------------------------------------------------
// prep: W1bT[kc][n][e] = bf16(W1[n][512 + kc*8 + e])  (k-chunk-major so the
// fused kernel loads B fragments straight from L2, coalesced);
// uprime[b][a] = b1[a] + W1[a,:512].input[b]
// ---------------------------------------------------------------------------
__global__ __launch_bounds__(256) void prep_kernel(
    const float* __restrict__ W1, const float* __restrict__ b1,
    const float* __restrict__ input, unsigned short* __restrict__ W1bT,
    float* __restrict__ uprime) {
  __shared__ float w1row[1024];
  const int a = blockIdx.x;
  const int t = threadIdx.x;
  float4 v = *(const float4*)(W1 + a * 1024 + t * 4);
  *(float4*)(w1row + t * 4) = v;
  if (t >= 128) {
    ushort4 u;
    u.x = f2bf(v.x); u.y = f2bf(v.y); u.z = f2bf(v.z); u.w = f2bf(v.w);
    const int d = t * 4 - 512;       // 0..508 step 4
    const int kc = d >> 3;           // k-chunk 0..63
    const int e = d & 7;             // 0 or 4
    *(ushort4*)(W1bT + ((size_t)kc * 512 + a) * 8 + e) = u;
  }
  __syncthreads();
  if (t < BATCH) {
    const float4* inp = (const float4*)(input + t * 512);
    const float4* wr = (const float4*)w1row;
    float acc = b1[a];
#pragma unroll 4
    for (int d = 0; d < 128; ++d) {
      float4 x = inp[d], w = wr[d];
      acc += x.x * w.x + x.y * w.y + x.z * w.z + x.w * w.w;
    }
    uprime[t * 512 + a] = acc;  // [b][a]
  }
}

// ---------------------------------------------------------------------------
// fused v9: block = (b, c) with c a 64-s chunk; grid 2048 (b fast: bx&63).
// Phase 1 (v7 GEMM verbatim): stage 64 strided src rows (s=c*64..+63, slice b)
// as bf16 into LDS (XOR-chunk swizzle), ONE barrier, then 16 barrier-free
// K-steps: B from L2-resident W1bT -> VGPR, A via ds_read_b128, acc[4][8].
// Phase 2: tanh + W2 dot -> 64 chunk scores in LDS (mask applied), store
// masked scores to scores_t[b][s].
// Phase 3: chunk-local softmax (m_c, l_c, ptilde in LDS).
// Phase 4: partial O[512] = sum_s ptilde_s * src_row(s,b) -- f32 re-read,
// L2-hot (rows were staged by this block). Store O_c (2 KB) + (m_c,l_c).
// combine_kernel then does the global flash-rescale.
// This removes the separate softmax + ctx_partial + ctx_reduce kernels and
// one full 256 MB pass over src.
// ---------------------------------------------------------------------------
__global__ __launch_bounds__(256, 2) void fused_kernel(
    const float* __restrict__ src, const unsigned short* __restrict__ W1bT,
    const float* __restrict__ uprime, const float* __restrict__ W2,
    const unsigned char* __restrict__ mask, float* __restrict__ scores_t,
    float* __restrict__ ml, float* __restrict__ partialO, int wpart) {
  __shared__ unsigned short A_sm[64 * 512];  // 64 KB, full-K A tile
  __shared__ float s_sc[64];   // chunk scores (accumulator, then masked)
  __shared__ float s_p[64];    // ptilde
  __shared__ float4 s_O[2][128];  // 4 KB, O-step half reduction

  const int t = threadIdx.x;
  const int b = blockIdx.x & 63;   // batch (fast-varying: adjacent blocks
  const int c = blockIdx.x >> 6;   // read adjacent slices of same rows)
  const int w = t >> 6;            // wave 0..3 (uniform)
  const int lane = t & 63;
  const int quad = lane >> 4;
  const int l15 = lane & 15;

  if (t < 64) s_sc[t] = 0.f;

  f32x4 acc[4][8];
#pragma unroll
  for (int i = 0; i < 4; ++i)
#pragma unroll
    for (int j = 0; j < 8; ++j) acc[i][j] = (f32x4){0.f, 0.f, 0.f, 0.f};

  // ---- stage A tile: 64 s-rows (slice b) x 512 f32 -> bf16, swizzled ----
  {
    const float4* sf4 = (const float4*)src;
    const int cc = t & 63;
#pragma unroll 4
    for (int n = 0; n < 16; ++n) {
      const int row = n * 4 + (t >> 6);  // s-local row
      const float4* grow = sf4 + ((size_t)(c * 64 + row) * 64 + b) * 128;
      const float4 v0 = grow[cc * 2];
      const float4 v1 = grow[cc * 2 + 1];
      u32x4 o;
      o.x = pkbf(v0.x, v0.y);
      o.y = pkbf(v0.z, v0.w);
      o.z = pkbf(v1.x, v1.y);
      o.w = pkbf(v1.z, v1.w);
      const int p = cc ^ (row & 7);
      *(u32x4*)(A_sm + row * 512 + p * 8) = o;
    }
  }
  __syncthreads();  // the ONLY barrier before epilogue

  // ---- K-loop: 16 steps of K=32, no barriers (v7 verbatim) ----
  const unsigned short* gB = W1bT + ((size_t)quad * 512 + w * 128 + l15) * 8;
#pragma unroll 4
  for (int n = 0; n < 16; ++n) {
    bf16x8 bb[8], af[4];
#pragma unroll
    for (int j = 0; j < 8; ++j)
      bb[j] = *(const bf16x8*)(gB + ((size_t)n * 4 * 512 + j * 16) * 8);
    const int cch = n * 4 + quad;  // global 16B k-chunk 0..63
#pragma unroll
    for (int i = 0; i < 4; ++i) {
      const int r = i * 16 + l15;
      af[i] = *(const bf16x8*)(A_sm + r * 512 + ((cch ^ (r & 7)) << 3));
    }
#pragma unroll
    for (int i = 0; i < 4; ++i)
#pragma unroll
      for (int j = 0; j < 8; ++j)
        acc[i][j] = __builtin_amdgcn_mfma_f32_16x16x32_bf16(af[i], bb[j],
                                                            acc[i][j], 0, 0, 0);
  }

  // ---- epilogue: tanh + W2 partial dot over this wave's 128 cols ----
  // uprime contribution is per-COLUMN now (batch b fixed for whole block).
  float w2r[8], upr[8];
#pragma unroll
  for (int j = 0; j < 8; ++j) {
    w2r[j] = W2[w * 128 + j * 16 + l15];
    upr[j] = uprime[b * 512 + w * 128 + j * 16 + l15];
  }

#pragma unroll
  for (int i = 0; i < 4; ++i) {
#pragma unroll
    for (int r = 0; r < 4; ++r) {
      const int sl = i * 16 + quad * 4 + r;  // s-local row 0..63
      float sp = 0.f;
#pragma unroll
      for (int j = 0; j < 8; ++j)
        sp += w2r[j] * tanh_fast(acc[i][j][r] + upr[j]);
      sp += __shfl_xor(sp, 1);
      sp += __shfl_xor(sp, 2);
      sp += __shfl_xor(sp, 4);
      sp += __shfl_xor(sp, 8);
      if (l15 == 0) atomicAdd(&s_sc[sl], sp);
    }
  }
  __syncthreads();

  // ---- chunk-local softmax ----
  if (t < 64) {
    float sc = s_sc[t];
    if (mask[(size_t)(c * 64 + t) * BATCH + b]) sc = -__builtin_inff();
    s_sc[t] = sc;
    scores_t[b * S_LEN + c * 64 + t] = sc;  // masked score, [b][s]
  }
  __syncthreads();
  float mc = -__builtin_inff();
#pragma unroll
  for (int k = 0; k < 64; ++k) mc = fmaxf(mc, s_sc[k]);  // LDS broadcast reads
  if (t < 64) {
    const float sc = s_sc[t];
    s_p[t] = (mc == -__builtin_inff()) ? 0.f : __expf(sc - mc);
  }
  __syncthreads();
  if (wpart && t == 0) {
    float l = 0.f;
#pragma unroll
    for (int k = 0; k < 64; ++k) l += s_p[k];
    ml[(b * 32 + c) * 2] = mc;
    ml[(b * 32 + c) * 2 + 1] = l;
  }

  if (!wpart) return;  // fallback path computes ctx separately

  // ---- partial O: O[d] = sum_s ptilde_s * src[s][b][d]  (f32, L2-hot) ----
  {
    const int f4i = t & 127;
    const int sh = t >> 7;
    const float4* base =
        (const float4*)src + ((size_t)(c * 64 + sh * 32) * 64 + b) * 128 + f4i;
    float4 a4 = {0.f, 0.f, 0.f, 0.f};
#pragma unroll 8
    for (int i = 0; i < 32; ++i) {
      const float p = s_p[sh * 32 + i];
      float4 v = base[(size_t)i * 8192];  // next s: +64*512 floats
      a4.x += p * v.x; a4.y += p * v.y; a4.z += p * v.z; a4.w += p * v.w;
    }
    s_O[sh][f4i] = a4;
  }
  __syncthreads();
  if (t < 128) {
    float4 o0 = s_O[0][t], o1 = s_O[1][t];
    float4 o = {o0.x + o1.x, o0.y + o1.y, o0.z + o1.z, o0.w + o1.w};
    ((float4*)partialO)[(size_t)(b * 32 + c) * 128 + t] = o;
  }
}

// ---------------------------------------------------------------------------
// combine: per b, global flash-rescale of the 32 chunk partials.
// ctx[b][d] = sum_c e^{m_c-m} O_c[d] / L,  L = sum_c l_c e^{m_c-m};
// attn[s][b] = e^{score-m}/L.
// ---------------------------------------------------------------------------
__global__ __launch_bounds__(256) void combine_kernel(
    const float* __restrict__ scores_t, const float* __restrict__ ml,
    const float* __restrict__ partialO, float* __restrict__ ctx,
    float* __restrict__ attn) {
  __shared__ float sm[32], sl[32], ss[32];
  const int b = blockIdx.x, t = threadIdx.x;
  if (t < 32) {
    sm[t] = ml[(b * 32 + t) * 2];
    sl[t] = ml[(b * 32 + t) * 2 + 1];
  }
  __syncthreads();
  float m = -__builtin_inff();
#pragma unroll
  for (int c = 0; c < 32; ++c) m = fmaxf(m, sm[c]);
  if (t < 32) ss[t] = (sl[t] > 0.f) ? __expf(sm[t] - m) : 0.f;
  __syncthreads();
  float L = 0.f;
#pragma unroll
  for (int c = 0; c < 32; ++c) L += sl[c] * ss[c];
  const float invL = 1.f / L;

  // ctx: thread owns 2 d (float2)
  float2 a = {0.f, 0.f};
  const float2* po = (const float2*)partialO + (size_t)b * 32 * 256 + t;
#pragma unroll 8
  for (int c = 0; c < 32; ++c) {
    float2 v = po[c * 256];
    a.x += ss[c] * v.x;
    a.y += ss[c] * v.y;
  }
  float2 o = {a.x * invL, a.y * invL};
  ((float2*)ctx)[b * 256 + t] = o;

  // attn
#pragma unroll
  for (int k = 0; k < 8; ++k) {
    const int s = k * 256 + t;
    const float p = __expf(scores_t[b * S_LEN + s] - m) * invL;
    attn[s * BATCH + b] = p;
  }
}

// ---------------------------------------------------------------------------
// Fallback (small ws): old softmax over scores_t + atomic ctx.
// ---------------------------------------------------------------------------
__global__ __launch_bounds__(256) void softmax_kernel(
    const float* __restrict__ scores_t, const unsigned char* __restrict__ mask,
    float* __restrict__ attn_g) {
  __shared__ float red[256];
  const int b = blockIdx.x, t = threadIdx.x;
  float m = -__builtin_inff();
  float sc[8];
#pragma unroll
  for (int c = 0; c < 8; ++c) {
    const int s = t + c * 256;
    sc[c] = mask[s * BATCH + b] ? -__builtin_inff() : scores_t[b * S_LEN + s];
    m = fmaxf(m, sc[c]);
  }
  red[t] = m;
  __syncthreads();
  for (int off = 128; off; off >>= 1) {
    if (t < off) red[t] = fmaxf(red[t], red[t + off]);
    __syncthreads();
  }
  m = red[0];
  __syncthreads();
  float sum = 0.f;
#pragma unroll
  for (int c = 0; c < 8; ++c) sum += __expf(sc[c] - m);
  red[t] = sum;
  __syncthreads();
  for (int off = 128; off; off >>= 1) {
    if (t < off) red[t] += red[t + off];
    __syncthreads();
  }
  const float inv = 1.f / red[0];
#pragma unroll
  for (int c = 0; c < 8; ++c) {
    const int s = t + c * 256;
    attn_g[s * BATCH + b] = __expf(sc[c] - m) * inv;
  }
}

__global__ __launch_bounds__(256) void ctx_atomic_kernel(
    const float* __restrict__ src, const float* __restrict__ attn_g,
    float* __restrict__ ctx) {
  __shared__ float a_lds[128];
  const int s0 = blockIdx.x * 128, b = blockIdx.y, t = threadIdx.x;
  if (t < 128) a_lds[t] = attn_g[(s0 + t) * BATCH + b];
  __syncthreads();
  const int f4i = t & 127;
  const int sh = t >> 7;
  const float4* base =
      (const float4*)src + ((size_t)(s0 + sh * 64) * BATCH + b) * 128 + f4i;
  float4 acc = {0.f, 0.f, 0.f, 0.f};
#pragma unroll 8
  for (int i = 0; i < 64; ++i) {
    const float a = a_lds[sh * 64 + i];
    float4 v = base[(size_t)i * BATCH * 128];
    acc.x += a * v.x; acc.y += a * v.y; acc.z += a * v.z; acc.w += a * v.w;
  }
  float* cp = ctx + b * DDIM + f4i * 4;
  atomicAdd(cp + 0, acc.x);
  atomicAdd(cp + 1, acc.y);
  atomicAdd(cp + 2, acc.z);
  atomicAdd(cp + 3, acc.w);
}

// ---------------------------------------------------------------------------
extern "C" void kernel_launch(void* const* d_in, const int* in_sizes, int n_in,
                              void* d_out, int out_size, void* d_ws, size_t ws_size,
                              hipStream_t stream) {
  const float* input = (const float*)d_in[0];
  const float* src = (const float*)d_in[1];
  const unsigned char* mask = (const unsigned char*)d_in[2];
  const float* W1 = (const float*)d_in[3];
  const float* b1 = (const float*)d_in[4];
  const float* W2 = (const float*)d_in[5];
  // d_in[6] = b2: omitted (constant shift cancels in softmax)

  float* ctx = (float*)d_out;                  // [64,512]
  float* attn = (float*)d_out + BATCH * DDIM;  // [2048,64]

  // ws layout
  unsigned short* W1bT = (unsigned short*)d_ws;               // 512 KB @ 0
  float* uprime = (float*)((char*)d_ws + 512 * 1024);         // 128 KB
  float* scores_t = (float*)((char*)d_ws + 640 * 1024);       // 512 KB
  float* ml = (float*)((char*)d_ws + 1152 * 1024);            // 16 KB
  float* partialO = (float*)((char*)d_ws + 1168 * 1024);      // 4 MB
  const size_t NEED_FUSED = 1168 * 1024 + (size_t)64 * 32 * 512 * 4;
  const int wpart = ws_size >= NEED_FUSED;

  prep_kernel<<<512, 256, 0, stream>>>(W1, b1, input, W1bT, uprime);
  fused_kernel<<<2048, 256, 0, stream>>>(src, W1bT, uprime, W2, mask, scores_t,
                                         ml, partialO, wpart);
  if (wpart) {
    combine_kernel<<<BATCH, 256, 0, stream>>>(scores_t, ml, partialO, ctx, attn);
  } else {
    softmax_kernel<<<BATCH, 256, 0, stream>>>(scores_t, mask, attn);
    hipMemsetAsync(ctx, 0, BATCH * DDIM * sizeof(float), stream);
    ctx_atomic_kernel<<<dim3(16, BATCH), 256, 0, stream>>>(src, attn, ctx);
  }
}

// Round 6
// 470.609 us; speedup vs baseline: 1.1176x; 1.0137x over previous
//
#include <hip/hip_runtime.h>
#include <hip/hip_bf16.h>
#include <math.h>

// Problem constants (S, B, D_IN, D_SRC, D_ALIGN = 2048, 64, 512, 512, 512)
#define S_LEN 2048
#define BATCH 64
#define DDIM 512

typedef __attribute__((ext_vector_type(8))) short bf16x8;
typedef __attribute__((ext_vector_type(4))) float f32x4;
typedef __attribute__((ext_vector_type(4))) unsigned int u32x4;

__device__ __forceinline__ unsigned short f2bf(float f) {
  unsigned int u = __float_as_uint(f);
  u += 0x7fffu + ((u >> 16) & 1u);
  return (unsigned short)(u >> 16);
}

__device__ __forceinline__ float tanh_fast(float x) {
  // tanh(x) = 1 - 2/(exp2(2*log2e*x)+1)
  float e = __builtin_amdgcn_exp2f(x * 2.88539008177793f);
  return 1.0f - 2.0f * __builtin_amdgcn_rcpf(e + 1.0f);
}

// pack two f32 into bf16x2 (lo=a, hi=b), round-half-up (matches prior kernel)
__device__ __forceinline__ unsigned pkbf(float a, float b) {
  unsigned ua = __float_as_uint(a) + 0x8000u;
  unsigned ub = __float_as_uint(b) + 0x8000u;
  return __builtin_amdgcn_perm(ub, ua, 0x07060302u);
}

// ---------------------------------------------------------------------------
// prep: W1bT[kc][n][e] = bf16(W1[n][512 + kc*8 + e])  (k-chunk-major so the
// fused kernel loads B fragments straight from L2, coalesced);
// uprime[b][a] = b1[a] + W1[a,:512].input[b]
// ---------------------------------------------------------------------------
__global__ __launch_bounds__(256) void prep_kernel(
    const float* __restrict__ W1, const float* __restrict__ b1,
    const float* __restrict__ input, unsigned short* __restrict__ W1bT,
    float* __restrict__ uprime) {
  __shared__ float w1row[1024];
  const int a = blockIdx.x;
  const int t = threadIdx.x;
  float4 v = *(const float4*)(W1 + a * 1024 + t * 4);
  *(float4*)(w1row + t * 4) = v;
  if (t >= 128) {
    ushort4 u;
    u.x = f2bf(v.x); u.y = f2bf(v.y); u.z = f2bf(v.z); u.w = f2bf(v.w);
    const int d = t * 4 - 512;       // 0..508 step 4
    const int kc = d >> 3;           // k-chunk 0..63
    const int e = d & 7;             // 0 or 4
    *(ushort4*)(W1bT + ((size_t)kc * 512 + a) * 8 + e) = u;
  }
  __syncthreads();
  if (t < BATCH) {
    const float4* inp = (const float4*)(input + t * 512);
    const float4* wr = (const float4*)w1row;
    float acc = b1[a];
#pragma unroll 4
    for (int d = 0; d < 128; ++d) {
      float4 x = inp[d], w = wr[d];
      acc += x.x * w.x + x.y * w.y + x.z * w.z + x.w * w.w;
    }
    uprime[t * 512 + a] = acc;  // [b][a]
  }
}

// ---------------------------------------------------------------------------
// fused v10: block = (b, c), grid 2048, 512 thr / 8 waves (was 256/4).
// Wave w owns 64 output cols -> acc[4][4] (64 AGPR); working VGPR ~60 ->
// ~124 unified regs, __launch_bounds__(512,4) => 4 waves/SIMD, 16 waves/CU
// (2x v9). LDS 74.5 KB -> 2 blocks/CU. Four waves per SIMD interleave: one
// MFMAs while others wait on L2/HBM -- this is the occupancy fix for the
// latency-serialization that pinned v4..v9 at 165-205 us.
// Phases (v9 verbatim, re-indexed): stage 64 s-rows (slice b) as bf16 into
// LDS (XOR-chunk swizzle), ONE barrier, 16 barrier-free K-steps (B from
// L2-resident W1bT, A via ds_read_b128), tanh+W2 epilogue, chunk-local
// softmax, partial O from f32 re-read. combine_kernel does the global
// flash-rescale.
// ---------------------------------------------------------------------------
__global__ __launch_bounds__(512, 4) void fused_kernel(
    const float* __restrict__ src, const unsigned short* __restrict__ W1bT,
    const float* __restrict__ uprime, const float* __restrict__ W2,
    const unsigned char* __restrict__ mask, float* __restrict__ scores_t,
    float* __restrict__ ml, float* __restrict__ partialO, int wpart) {
  __shared__ unsigned short A_sm[64 * 512];  // 64 KB, full-K A tile
  __shared__ float s_sc[64];      // chunk scores (accumulator, then masked)
  __shared__ float s_p[64];       // ptilde
  __shared__ float4 s_O[4][128];  // 8 KB, O-step quarter reduction

  const int t = threadIdx.x;
  const int b = blockIdx.x & 63;   // batch (fast-varying: adjacent blocks
  const int c = blockIdx.x >> 6;   // read adjacent slices of same rows)
  const int w = t >> 6;            // wave 0..7 (uniform)
  const int lane = t & 63;
  const int quad = lane >> 4;
  const int l15 = lane & 15;

  if (t < 64) s_sc[t] = 0.f;

  f32x4 acc[4][4];
#pragma unroll
  for (int i = 0; i < 4; ++i)
#pragma unroll
    for (int j = 0; j < 4; ++j) acc[i][j] = (f32x4){0.f, 0.f, 0.f, 0.f};

  // ---- stage A tile: 64 s-rows (slice b) x 512 f32 -> bf16, swizzled ----
  // wave w handles row n*8+w (full 2 KB row across 64 lanes), n = 0..7.
  {
    const float4* sf4 = (const float4*)src;
    const int cc = t & 63;
#pragma unroll 2
    for (int n = 0; n < 8; ++n) {
      const int row = n * 8 + w;  // s-local row
      const float4* grow = sf4 + ((size_t)(c * 64 + row) * 64 + b) * 128;
      const float4 v0 = grow[cc * 2];
      const float4 v1 = grow[cc * 2 + 1];
      u32x4 o;
      o.x = pkbf(v0.x, v0.y);
      o.y = pkbf(v0.z, v0.w);
      o.z = pkbf(v1.x, v1.y);
      o.w = pkbf(v1.z, v1.w);
      const int p = cc ^ (row & 7);
      *(u32x4*)(A_sm + row * 512 + p * 8) = o;
    }
  }
  __syncthreads();  // the ONLY barrier before epilogue

  // ---- K-loop: 16 steps of K=32, no barriers ----
  const unsigned short* gB = W1bT + ((size_t)quad * 512 + w * 64 + l15) * 8;
#pragma unroll 4
  for (int n = 0; n < 16; ++n) {
    bf16x8 bb[4], af[4];
#pragma unroll
    for (int j = 0; j < 4; ++j)
      bb[j] = *(const bf16x8*)(gB + ((size_t)n * 4 * 512 + j * 16) * 8);
    const int cch = n * 4 + quad;  // global 16B k-chunk 0..63
#pragma unroll
    for (int i = 0; i < 4; ++i) {
      const int r = i * 16 + l15;
      af[i] = *(const bf16x8*)(A_sm + r * 512 + ((cch ^ (r & 7)) << 3));
    }
#pragma unroll
    for (int i = 0; i < 4; ++i)
#pragma unroll
      for (int j = 0; j < 4; ++j)
        acc[i][j] = __builtin_amdgcn_mfma_f32_16x16x32_bf16(af[i], bb[j],
                                                            acc[i][j], 0, 0, 0);
  }

  // ---- epilogue: tanh + W2 partial dot over this wave's 64 cols ----
  float w2r[4], upr[4];
#pragma unroll
  for (int j = 0; j < 4; ++j) {
    w2r[j] = W2[w * 64 + j * 16 + l15];
    upr[j] = uprime[b * 512 + w * 64 + j * 16 + l15];
  }

#pragma unroll
  for (int i = 0; i < 4; ++i) {
#pragma unroll
    for (int r = 0; r < 4; ++r) {
      const int sl = i * 16 + quad * 4 + r;  // s-local row 0..63
      float sp = 0.f;
#pragma unroll
      for (int j = 0; j < 4; ++j)
        sp += w2r[j] * tanh_fast(acc[i][j][r] + upr[j]);
      sp += __shfl_xor(sp, 1);
      sp += __shfl_xor(sp, 2);
      sp += __shfl_xor(sp, 4);
      sp += __shfl_xor(sp, 8);
      if (l15 == 0) atomicAdd(&s_sc[sl], sp);
    }
  }
  __syncthreads();

  // ---- chunk-local softmax ----
  if (t < 64) {
    float sc = s_sc[t];
    if (mask[(size_t)(c * 64 + t) * BATCH + b]) sc = -__builtin_inff();
    s_sc[t] = sc;
    scores_t[b * S_LEN + c * 64 + t] = sc;  // masked score, [b][s]
  }
  __syncthreads();
  float mc = -__builtin_inff();
#pragma unroll
  for (int k = 0; k < 64; ++k) mc = fmaxf(mc, s_sc[k]);  // LDS broadcast reads
  if (t < 64) {
    const float sc = s_sc[t];
    s_p[t] = (mc == -__builtin_inff()) ? 0.f : __expf(sc - mc);
  }
  __syncthreads();
  if (wpart && t == 0) {
    float l = 0.f;
#pragma unroll
    for (int k = 0; k < 64; ++k) l += s_p[k];
    ml[(b * 32 + c) * 2] = mc;
    ml[(b * 32 + c) * 2 + 1] = l;
  }

  if (!wpart) return;  // fallback path computes ctx separately

  // ---- partial O: O[d] = sum_s ptilde_s * src[s][b][d]  (f32) ----
  {
    const int f4i = t & 127;
    const int sh = t >> 7;  // 0..3, each covers 16 s
    const float4* base =
        (const float4*)src + ((size_t)(c * 64 + sh * 16) * 64 + b) * 128 + f4i;
    float4 a4 = {0.f, 0.f, 0.f, 0.f};
#pragma unroll 8
    for (int i = 0; i < 16; ++i) {
      const float p = s_p[sh * 16 + i];
      float4 v = base[(size_t)i * 8192];  // next s: +64*512 floats
      a4.x += p * v.x; a4.y += p * v.y; a4.z += p * v.z; a4.w += p * v.w;
    }
    s_O[sh][f4i] = a4;
  }
  __syncthreads();
  if (t < 128) {
    float4 o0 = s_O[0][t], o1 = s_O[1][t], o2 = s_O[2][t], o3 = s_O[3][t];
    float4 o = {o0.x + o1.x + o2.x + o3.x, o0.y + o1.y + o2.y + o3.y,
                o0.z + o1.z + o2.z + o3.z, o0.w + o1.w + o2.w + o3.w};
    ((float4*)partialO)[(size_t)(b * 32 + c) * 128 + t] = o;
  }
}

// ---------------------------------------------------------------------------
// combine: per b, global flash-rescale of the 32 chunk partials.
// ctx[b][d] = sum_c e^{m_c-m} O_c[d] / L,  L = sum_c l_c e^{m_c-m};
// attn[s][b] = e^{score-m}/L.
// ---------------------------------------------------------------------------
__global__ __launch_bounds__(256) void combine_kernel(
    const float* __restrict__ scores_t, const float* __restrict__ ml,
    const float* __restrict__ partialO, float* __restrict__ ctx,
    float* __restrict__ attn) {
  __shared__ float sm[32], sl[32], ss[32];
  const int b = blockIdx.x, t = threadIdx.x;
  if (t < 32) {
    sm[t] = ml[(b * 32 + t) * 2];
    sl[t] = ml[(b * 32 + t) * 2 + 1];
  }
  __syncthreads();
  float m = -__builtin_inff();
#pragma unroll
  for (int c = 0; c < 32; ++c) m = fmaxf(m, sm[c]);
  if (t < 32) ss[t] = (sl[t] > 0.f) ? __expf(sm[t] - m) : 0.f;
  __syncthreads();
  float L = 0.f;
#pragma unroll
  for (int c = 0; c < 32; ++c) L += sl[c] * ss[c];
  const float invL = 1.f / L;

  // ctx: thread owns 2 d (float2)
  float2 a = {0.f, 0.f};
  const float2* po = (const float2*)partialO + (size_t)b * 32 * 256 + t;
#pragma unroll 8
  for (int c = 0; c < 32; ++c) {
    float2 v = po[c * 256];
    a.x += ss[c] * v.x;
    a.y += ss[c] * v.y;
  }
  float2 o = {a.x * invL, a.y * invL};
  ((float2*)ctx)[b * 256 + t] = o;

  // attn
#pragma unroll
  for (int k = 0; k < 8; ++k) {
    const int s = k * 256 + t;
    const float p = __expf(scores_t[b * S_LEN + s] - m) * invL;
    attn[s * BATCH + b] = p;
  }
}

// ---------------------------------------------------------------------------
// Fallback (small ws): old softmax over scores_t + atomic ctx.
// ---------------------------------------------------------------------------
__global__ __launch_bounds__(256) void softmax_kernel(
    const float* __restrict__ scores_t, const unsigned char* __restrict__ mask,
    float* __restrict__ attn_g) {
  __shared__ float red[256];
  const int b = blockIdx.x, t = threadIdx.x;
  float m = -__builtin_inff();
  float sc[8];
#pragma unroll
  for (int c = 0; c < 8; ++c) {
    const int s = t + c * 256;
    sc[c] = mask[s * BATCH + b] ? -__builtin_inff() : scores_t[b * S_LEN + s];
    m = fmaxf(m, sc[c]);
  }
  red[t] = m;
  __syncthreads();
  for (int off = 128; off; off >>= 1) {
    if (t < off) red[t] = fmaxf(red[t], red[t + off]);
    __syncthreads();
  }
  m = red[0];
  __syncthreads();
  float sum = 0.f;
#pragma unroll
  for (int c = 0; c < 8; ++c) sum += __expf(sc[c] - m);
  red[t] = sum;
  __syncthreads();
  for (int off = 128; off; off >>= 1) {
    if (t < off) red[t] += red[t + off];
    __syncthreads();
  }
  const float inv = 1.f / red[0];
#pragma unroll
  for (int c = 0; c < 8; ++c) {
    const int s = t + c * 256;
    attn_g[s * BATCH + b] = __expf(sc[c] - m) * inv;
  }
}

__global__ __launch_bounds__(256) void ctx_atomic_kernel(
    const float* __restrict__ src, const float* __restrict__ attn_g,
    float* __restrict__ ctx) {
  __shared__ float a_lds[128];
  const int s0 = blockIdx.x * 128, b = blockIdx.y, t = threadIdx.x;
  if (t < 128) a_lds[t] = attn_g[(s0 + t) * BATCH + b];
  __syncthreads();
  const int f4i = t & 127;
  const int sh = t >> 7;
  const float4* base =
      (const float4*)src + ((size_t)(s0 + sh * 64) * BATCH + b) * 128 + f4i;
  float4 acc = {0.f, 0.f, 0.f, 0.f};
#pragma unroll 8
  for (int i = 0; i < 64; ++i) {
    const float a = a_lds[sh * 64 + i];
    float4 v = base[(size_t)i * BATCH * 128];
    acc.x += a * v.x; acc.y += a * v.y; acc.z += a * v.z; acc.w += a * v.w;
  }
  float* cp = ctx + b * DDIM + f4i * 4;
  atomicAdd(cp + 0, acc.x);
  atomicAdd(cp + 1, acc.y);
  atomicAdd(cp + 2, acc.z);
  atomicAdd(cp + 3, acc.w);
}

// ---------------------------------------------------------------------------
extern "C" void kernel_launch(void* const* d_in, const int* in_sizes, int n_in,
                              void* d_out, int out_size, void* d_ws, size_t ws_size,
                              hipStream_t stream) {
  const float* input = (const float*)d_in[0];
  const float* src = (const float*)d_in[1];
  const unsigned char* mask = (const unsigned char*)d_in[2];
  const float* W1 = (const float*)d_in[3];
  const float* b1 = (const float*)d_in[4];
  const float* W2 = (const float*)d_in[5];
  // d_in[6] = b2: omitted (constant shift cancels in softmax)

  float* ctx = (float*)d_out;                  // [64,512]
  float* attn = (float*)d_out + BATCH * DDIM;  // [2048,64]

  // ws layout
  unsigned short* W1bT = (unsigned short*)d_ws;               // 512 KB @ 0
  float* uprime = (float*)((char*)d_ws + 512 * 1024);         // 128 KB
  float* scores_t = (float*)((char*)d_ws + 640 * 1024);       // 512 KB
  float* ml = (float*)((char*)d_ws + 1152 * 1024);            // 16 KB
  float* partialO = (float*)((char*)d_ws + 1168 * 1024);      // 4 MB
  const size_t NEED_FUSED = 1168 * 1024 + (size_t)64 * 32 * 512 * 4;
  const int wpart = ws_size >= NEED_FUSED;

  prep_kernel<<<512, 256, 0, stream>>>(W1, b1, input, W1bT, uprime);
  fused_kernel<<<2048, 512, 0, stream>>>(src, W1bT, uprime, W2, mask, scores_t,
                                         ml, partialO, wpart);
  if (wpart) {
    combine_kernel<<<BATCH, 256, 0, stream>>>(scores_t, ml, partialO, ctx, attn);
  } else {
    softmax_kernel<<<BATCH, 256, 0, stream>>>(scores_t, mask, attn);
    hipMemsetAsync(ctx, 0, BATCH * DDIM * sizeof(float), stream);
    ctx_atomic_kernel<<<dim3(16, BATCH), 256, 0, stream>>>(src, attn, ctx);
  }
}